// Round 9
// baseline (811.421 us; speedup 1.0000x reference)
//
#include <hip/hip_runtime.h>

#define NN 50000
#define NE 800000
#define NB 196   // ceil(NN/256)

typedef float f32x4 __attribute__((ext_vector_type(4)));
typedef short s16x8 __attribute__((ext_vector_type(8)));
typedef unsigned short u16;

__device__ __forceinline__ u16 f2bf(float f) {
  union { float f; unsigned u; } v; v.f = f;
  unsigned r = v.u + 0x7FFFu + ((v.u >> 16) & 1u);
  return (u16)(r >> 16);
}

__device__ __forceinline__ void st_bf4(u16* p, f32x4 v) {
  ushort4 pv;
  pv.x = f2bf(v.x); pv.y = f2bf(v.y); pv.z = f2bf(v.z); pv.w = f2bf(v.w);
  *(ushort4*)p = pv;
}

// pack W[K x N] fp32 -> bf16, fragment-major for 16x16x32 MFMA B-operand
__device__ __forceinline__ void pack_one(const float* __restrict__ W, int N,
                                         u16* __restrict__ out, int t) {
  int j = t & 7, lane = (t >> 3) & 63, f = t >> 9;
  int NT = N >> 4;
  int nt = f % NT, ks = f / NT;
  int row = ks * 32 + ((lane >> 4) << 3) + j;
  int col = nt * 16 + (lane & 15);
  out[t] = f2bf(W[row * N + col]);
}

__global__ void pack_kernel(const float* __restrict__ We1, const float* __restrict__ We2,
                            const float* __restrict__ Wa1, const float* __restrict__ Wa2,
                            const float* __restrict__ Wn1, const float* __restrict__ Wn2,
                            u16* __restrict__ out) {
  int t = blockIdx.x * 256 + threadIdx.x;
  if (t < 24576)      pack_one(We1, 128, out,          t);
  else if (t < 32768) pack_one(We2, 64,  out + 24576,  t - 24576);
  else if (t < 57344) pack_one(Wa1, 128, out + 32768,  t - 32768);
  else if (t < 65536) pack_one(Wa2, 64,  out + 57344,  t - 57344);
  else if (t < 81920) pack_one(Wn1, 128, out + 65536,  t - 65536);
  else if (t < 90112) pack_one(Wn2, 64,  out + 81920,  t - 81920);
}

// ---- CSR build: histogram, 3-stage parallel scan, fill tuples ----

__global__ void count_kernel(const int* __restrict__ dst, int* __restrict__ cnt) {
  int e = blockIdx.x * 256 + threadIdx.x;
  if (e < NE) atomicAdd(cnt + dst[e], 1);
}

// stage 1: per-block exclusive scan of cnt; block totals to bsum
__global__ __launch_bounds__(256)
void scan1_kernel(const int* __restrict__ cnt, int* __restrict__ part,
                  int* __restrict__ bsum) {
  int b = blockIdx.x, t = threadIdx.x;
  int i = b * 256 + t;
  int v = (i < NN) ? cnt[i] : 0;
  int lane = t & 63, wv = t >> 6;
  int s = v;
  #pragma unroll
  for (int d = 1; d < 64; d <<= 1) {
    int u = __shfl_up(s, d, 64);
    if (lane >= d) s += u;
  }
  __shared__ int ws[4];
  if (lane == 63) ws[wv] = s;
  __syncthreads();
  int add = 0;
  #pragma unroll
  for (int k = 0; k < 3; ++k) if (k < wv) add += ws[k];
  s += add;
  if (i < NN) part[i] = s - v;     // exclusive within block
  if (t == 255) bsum[b] = s;       // block total
}

// stage 2: exclusive scan of the NB block totals (single tiny block)
__global__ __launch_bounds__(256)
void scan2_kernel(const int* __restrict__ bsum, int* __restrict__ bbase) {
  int t = threadIdx.x;
  int v = (t < NB) ? bsum[t] : 0;
  int lane = t & 63, wv = t >> 6;
  int s = v;
  #pragma unroll
  for (int d = 1; d < 64; d <<= 1) {
    int u = __shfl_up(s, d, 64);
    if (lane >= d) s += u;
  }
  __shared__ int ws[4];
  if (lane == 63) ws[wv] = s;
  __syncthreads();
  int add = 0;
  #pragma unroll
  for (int k = 0; k < 3; ++k) if (k < wv) add += ws[k];
  s += add;
  if (t < NB) bbase[t] = s - v;    // exclusive block base
}

// stage 3: cursor[i] = part[i] + bbase[block]
__global__ __launch_bounds__(256)
void scan3_kernel(const int* __restrict__ part, const int* __restrict__ bbase,
                  int* __restrict__ cursor) {
  int b = blockIdx.x, t = threadIdx.x;
  int i = b * 256 + t;
  if (i < NN) cursor[i] = part[i] + bbase[b];
}

// fill: emit dst-sorted tuples {src, dst, e, 0}
__global__ void fill_kernel(const int* __restrict__ src, const int* __restrict__ dst,
                            int* __restrict__ cursor, int4* __restrict__ tup) {
  int e = blockIdx.x * 256 + threadIdx.x;
  if (e < NE) {
    int d = dst[e];
    int slot = atomicAdd(cursor + d, 1);
    int4 t4; t4.x = src[e]; t4.y = d; t4.z = e; t4.w = 0;
    tup[slot] = t4;
  }
}

// ---- shared MLP cores ----

__device__ __forceinline__ void edge_mlps(
    u16* xe /*stride 200*/, u16* hs /*stride 136*/, int lane,
    const u16* __restrict__ W1e, const float* __restrict__ b1e, const u16* __restrict__ W2e,
    const u16* __restrict__ W1a, const float* __restrict__ b1a, const u16* __restrict__ W2a,
    f32x4 eo[4], f32x4 go[4]) {
  const int m = lane & 15, q = lane >> 4;
  s16x8 a1[6];
  #pragma unroll
  for (int k = 0; k < 6; ++k)
    a1[k] = *(const s16x8*)(xe + m * 200 + k * 32 + q * 8);

  // e-MLP layer 1: [16x192] @ [192x128]
  f32x4 acc[8];
  #pragma unroll
  for (int i = 0; i < 8; ++i) { acc[i][0] = 0.f; acc[i][1] = 0.f; acc[i][2] = 0.f; acc[i][3] = 0.f; }
  #pragma unroll
  for (int nt = 0; nt < 8; ++nt)
    #pragma unroll
    for (int k = 0; k < 6; ++k) {
      s16x8 b = *(const s16x8*)(W1e + ((size_t)(k * 8 + nt) * 64 + lane) * 8);
      acc[nt] = __builtin_amdgcn_mfma_f32_16x16x32_bf16(a1[k], b, acc[nt], 0, 0, 0);
    }
  #pragma unroll
  for (int nt = 0; nt < 8; ++nt) {
    float bv = b1e[nt * 16 + m];
    #pragma unroll
    for (int r = 0; r < 4; ++r) {
      float h = acc[nt][r] + bv;
      h = h > 0.f ? h : 0.f;
      hs[(q * 4 + r) * 136 + nt * 16 + m] = f2bf(h);
    }
  }
  __syncthreads();

  // e-MLP layer 2: [16x128] @ [128x64]
  s16x8 a2[4];
  #pragma unroll
  for (int k = 0; k < 4; ++k)
    a2[k] = *(const s16x8*)(hs + m * 136 + k * 32 + q * 8);
  #pragma unroll
  for (int i = 0; i < 4; ++i) { eo[i][0] = 0.f; eo[i][1] = 0.f; eo[i][2] = 0.f; eo[i][3] = 0.f; }
  #pragma unroll
  for (int nt = 0; nt < 4; ++nt)
    #pragma unroll
    for (int k = 0; k < 4; ++k) {
      s16x8 b = *(const s16x8*)(W2e + ((size_t)(k * 4 + nt) * 64 + lane) * 8);
      eo[nt] = __builtin_amdgcn_mfma_f32_16x16x32_bf16(a2[k], b, eo[nt], 0, 0, 0);
    }

  // gate-MLP layer 1 (reuses a1)
  f32x4 accg[8];
  #pragma unroll
  for (int i = 0; i < 8; ++i) { accg[i][0] = 0.f; accg[i][1] = 0.f; accg[i][2] = 0.f; accg[i][3] = 0.f; }
  #pragma unroll
  for (int nt = 0; nt < 8; ++nt)
    #pragma unroll
    for (int k = 0; k < 6; ++k) {
      s16x8 b = *(const s16x8*)(W1a + ((size_t)(k * 8 + nt) * 64 + lane) * 8);
      accg[nt] = __builtin_amdgcn_mfma_f32_16x16x32_bf16(a1[k], b, accg[nt], 0, 0, 0);
    }
  __syncthreads();   // a2 reads done before hs overwrite
  #pragma unroll
  for (int nt = 0; nt < 8; ++nt) {
    float bv = b1a[nt * 16 + m];
    #pragma unroll
    for (int r = 0; r < 4; ++r) {
      float h = accg[nt][r] + bv;
      h = h > 0.f ? h : 0.f;
      hs[(q * 4 + r) * 136 + nt * 16 + m] = f2bf(h);
    }
  }
  __syncthreads();

  // gate-MLP layer 2
  s16x8 a2g[4];
  #pragma unroll
  for (int k = 0; k < 4; ++k)
    a2g[k] = *(const s16x8*)(hs + m * 136 + k * 32 + q * 8);
  #pragma unroll
  for (int i = 0; i < 4; ++i) { go[i][0] = 0.f; go[i][1] = 0.f; go[i][2] = 0.f; go[i][3] = 0.f; }
  #pragma unroll
  for (int nt = 0; nt < 4; ++nt)
    #pragma unroll
    for (int k = 0; k < 4; ++k) {
      s16x8 b = *(const s16x8*)(W2a + ((size_t)(k * 4 + nt) * 64 + lane) * 8);
      go[nt] = __builtin_amdgcn_mfma_f32_16x16x32_bf16(a2g[k], b, go[nt], 0, 0, 0);
    }
}

__device__ __forceinline__ void node_mlp(
    u16* xn /*stride 136*/, u16* hn /*stride 136*/, int lane,
    const u16* __restrict__ W1n, const float* __restrict__ b1n, const u16* __restrict__ W2n,
    f32x4 o[4]) {
  const int m = lane & 15, q = lane >> 4;
  s16x8 a1[4];
  #pragma unroll
  for (int k = 0; k < 4; ++k)
    a1[k] = *(const s16x8*)(xn + m * 136 + k * 32 + q * 8);
  f32x4 acc[8];
  #pragma unroll
  for (int i = 0; i < 8; ++i) { acc[i][0] = 0.f; acc[i][1] = 0.f; acc[i][2] = 0.f; acc[i][3] = 0.f; }
  #pragma unroll
  for (int nt = 0; nt < 8; ++nt)
    #pragma unroll
    for (int k = 0; k < 4; ++k) {
      s16x8 b = *(const s16x8*)(W1n + ((size_t)(k * 8 + nt) * 64 + lane) * 8);
      acc[nt] = __builtin_amdgcn_mfma_f32_16x16x32_bf16(a1[k], b, acc[nt], 0, 0, 0);
    }
  #pragma unroll
  for (int nt = 0; nt < 8; ++nt) {
    float bv = b1n[nt * 16 + m];
    #pragma unroll
    for (int r = 0; r < 4; ++r) {
      float h = acc[nt][r] + bv;
      h = h > 0.f ? h : 0.f;
      hn[(q * 4 + r) * 136 + nt * 16 + m] = f2bf(h);
    }
  }
  __syncthreads();
  s16x8 a2[4];
  #pragma unroll
  for (int k = 0; k < 4; ++k)
    a2[k] = *(const s16x8*)(hn + m * 136 + k * 32 + q * 8);
  #pragma unroll
  for (int i = 0; i < 4; ++i) { o[i][0] = 0.f; o[i][1] = 0.f; o[i][2] = 0.f; o[i][3] = 0.f; }
  #pragma unroll
  for (int nt = 0; nt < 4; ++nt)
    #pragma unroll
    for (int k = 0; k < 4; ++k) {
      s16x8 b = *(const s16x8*)(W2n + ((size_t)(k * 4 + nt) * 64 + lane) * 8);
      o[nt] = __builtin_amdgcn_mfma_f32_16x16x32_bf16(a2[k], b, o[nt], 0, 0, 0);
    }
}

// ---- edge kernel, dst-sorted: writes out_ef + segment-reduced atomics to agg ----
// Fast path (whole 16-row tile one dst): shfl-reduce across q groups, 1 atomic/col.
// Slow path: per-lane run over its 4 rows, flushed at dst boundaries AND at the
// lane's last row (r==3) — partial segment sums from different lanes combine
// via atomicAdd (R8 bug: missing r==3 flush dropped partials).

__global__ __launch_bounds__(256, 3)
void edge_sorted(const float* __restrict__ nf, const float* __restrict__ ef,
                 const int4* __restrict__ tup,
                 const u16* __restrict__ W1e, const float* __restrict__ b1e,
                 const u16* __restrict__ W2e, const float* __restrict__ b2e,
                 const u16* __restrict__ W1a, const float* __restrict__ b1a,
                 const u16* __restrict__ W2a, const float* __restrict__ b2a,
                 float* __restrict__ out_ef, float* __restrict__ agg) {
  __shared__ u16 xe[4][16 * 200];
  __shared__ u16 hs[4][16 * 136];
  __shared__ int se[4][16];
  __shared__ int sdst[4][16];
  const int w = threadIdx.x >> 6, lane = threadIdx.x & 63;
  // bijective XCD swizzle (nwg = 12500: q=1562, r=4)
  const int nwg = gridDim.x;
  const int qq = nwg >> 3, rr = nwg & 7;
  const int xcd = blockIdx.x & 7, idx = blockIdx.x >> 3;
  const int bid = (xcd < rr ? xcd * (qq + 1) : rr * (qq + 1) + (xcd - rr) * qq) + idx;
  const int e0 = bid * 64 + w * 16;            // slot base
  const int er = lane >> 4, c4 = (lane & 15) * 4;

  #pragma unroll
  for (int g = 0; g < 4; ++g) {
    int el = g * 4 + er;
    int slot = e0 + el;
    int4 t4 = tup[slot];
    if (c4 == 0) { se[w][el] = t4.z; sdst[w][el] = t4.y; }
    f32x4 fs = *(const f32x4*)(nf + (size_t)t4.x * 64 + c4);
    f32x4 fd = *(const f32x4*)(nf + (size_t)t4.y * 64 + c4);
    f32x4 fe = *(const f32x4*)(ef + (size_t)t4.z * 64 + c4);
    u16* row = &xe[w][el * 200];
    st_bf4(row + c4, fs);
    st_bf4(row + 64 + c4, fd);
    st_bf4(row + 128 + c4, fe);
  }
  __syncthreads();

  f32x4 eo[4], go[4];
  edge_mlps(xe[w], hs[w], lane, W1e, b1e, W2e, W1a, b1a, W2a, eo, go);

  const int m = lane & 15, q = lane >> 4;
  const int d0 = sdst[w][0], d15 = sdst[w][15];
  const bool uni = (d0 == d15);                 // wave-uniform branch
  #pragma unroll
  for (int nt = 0; nt < 4; ++nt) {
    int col = nt * 16 + m;
    float be2v = b2e[col], ba2v = b2a[col];
    float vals[4];
    #pragma unroll
    for (int r = 0; r < 4; ++r) {
      int rowi = q * 4 + r;
      float ev = eo[nt][r] + be2v;
      float gv = go[nt][r] + ba2v;
      float gs = 1.f / (1.f + __expf(-gv));
      float val = gs * ev;
      out_ef[(size_t)se[w][rowi] * 64 + col] = val;   // original edge order
      vals[r] = val;
    }
    if (uni) {
      float s = (vals[0] + vals[1]) + (vals[2] + vals[3]);
      s += __shfl_xor(s, 16, 64);
      s += __shfl_xor(s, 32, 64);
      if (q == 0) atomicAdd(agg + (size_t)d0 * 64 + col, s);
    } else {
      float run = 0.f;
      #pragma unroll
      for (int r = 0; r < 4; ++r) {
        int rowi = q * 4 + r;
        run += vals[r];
        // flush at dst boundary OR end of this lane's 4 rows (partial sums
        // from adjacent lanes combine via atomicAdd)
        if (r == 3 || sdst[w][rowi] != sdst[w][rowi + 1]) {
          atomicAdd(agg + (size_t)sdst[w][rowi] * 64 + col, run);
          run = 0.f;
        }
      }
    }
  }
}

// ---- fallback edge kernel: plain atomics (small-workspace path) ----

__global__ __launch_bounds__(256, 3)
void edge_atomic(const float* __restrict__ nf, const float* __restrict__ ef,
                 const int* __restrict__ src, const int* __restrict__ dst,
                 const u16* __restrict__ W1e, const float* __restrict__ b1e,
                 const u16* __restrict__ W2e, const float* __restrict__ b2e,
                 const u16* __restrict__ W1a, const float* __restrict__ b1a,
                 const u16* __restrict__ W2a, const float* __restrict__ b2a,
                 float* __restrict__ out_ef, float* __restrict__ agg) {
  __shared__ u16 xe[4][16 * 200];
  __shared__ u16 hs[4][16 * 136];
  __shared__ int sdst[4][16];
  const int w = threadIdx.x >> 6, lane = threadIdx.x & 63;
  const int e0 = blockIdx.x * 64 + w * 16;
  const int er = lane >> 4, c4 = (lane & 15) * 4;

  #pragma unroll
  for (int g = 0; g < 4; ++g) {
    int el = g * 4 + er;
    int e = e0 + el;
    int s = src[e], d = dst[e];
    if (c4 == 0) sdst[w][el] = d;
    f32x4 fs = *(const f32x4*)(nf + (size_t)s * 64 + c4);
    f32x4 fd = *(const f32x4*)(nf + (size_t)d * 64 + c4);
    f32x4 fe = *(const f32x4*)(ef + (size_t)e * 64 + c4);
    u16* row = &xe[w][el * 200];
    st_bf4(row + c4, fs);
    st_bf4(row + 64 + c4, fd);
    st_bf4(row + 128 + c4, fe);
  }
  __syncthreads();

  f32x4 eo[4], go[4];
  edge_mlps(xe[w], hs[w], lane, W1e, b1e, W2e, W1a, b1a, W2a, eo, go);

  const int m = lane & 15, q = lane >> 4;
  #pragma unroll
  for (int nt = 0; nt < 4; ++nt) {
    int col = nt * 16 + m;
    float be2v = b2e[col], ba2v = b2a[col];
    #pragma unroll
    for (int r = 0; r < 4; ++r) {
      int rowi = q * 4 + r;
      float ev = eo[nt][r] + be2v;
      float gv = go[nt][r] + ba2v;
      float gs = 1.f / (1.f + __expf(-gv));
      float val = gs * ev;
      out_ef[(size_t)(e0 + rowi) * 64 + col] = val;
      atomicAdd(agg + (size_t)sdst[w][rowi] * 64 + col, val);
    }
  }
}

// ---- node kernel: reads dense pre-aggregated agg ----

__global__ __launch_bounds__(256, 4)
void node_direct(const float* __restrict__ nf, const float* __restrict__ agg,
                 const u16* __restrict__ W1n, const float* __restrict__ b1n,
                 const u16* __restrict__ W2n, const float* __restrict__ b2n,
                 float* __restrict__ out_nf) {
  __shared__ u16 xn[4][16 * 136];
  __shared__ u16 hn[4][16 * 136];
  const int w = threadIdx.x >> 6, lane = threadIdx.x & 63;
  const int n0 = blockIdx.x * 64 + w * 16;
  const int er = lane >> 4, c4 = (lane & 15) * 4;

  #pragma unroll
  for (int g = 0; g < 4; ++g) {
    int nl = g * 4 + er;
    int n = n0 + nl; if (n >= NN) n = NN - 1;
    f32x4 fa = *(const f32x4*)(agg + (size_t)n * 64 + c4);
    f32x4 fn4 = *(const f32x4*)(nf + (size_t)n * 64 + c4);
    u16* row = &xn[w][nl * 136];
    st_bf4(row + c4, fa);
    st_bf4(row + 64 + c4, fn4);
  }
  __syncthreads();

  f32x4 o[4];
  node_mlp(xn[w], hn[w], lane, W1n, b1n, W2n, o);

  const int m = lane & 15, q = lane >> 4;
  #pragma unroll
  for (int nt = 0; nt < 4; ++nt) {
    int col = nt * 16 + m;
    float bv = b2n[col];
    #pragma unroll
    for (int r = 0; r < 4; ++r) {
      int n = n0 + q * 4 + r;
      if (n < NN) out_nf[(size_t)n * 64 + col] = o[nt][r] + bv;
    }
  }
}

extern "C" void kernel_launch(void* const* d_in, const int* in_sizes, int n_in,
                              void* d_out, int out_size, void* d_ws, size_t ws_size,
                              hipStream_t stream) {
  const float* nf  = (const float*)d_in[0];
  const float* ef  = (const float*)d_in[1];
  const int*   src = (const int*)d_in[2];
  const int*   dst = (const int*)d_in[3];
  const float* We1 = (const float*)d_in[4];
  const float* be1 = (const float*)d_in[5];
  const float* We2 = (const float*)d_in[6];
  const float* be2 = (const float*)d_in[7];
  const float* Wa1 = (const float*)d_in[8];
  const float* ba1 = (const float*)d_in[9];
  const float* Wa2 = (const float*)d_in[10];
  const float* ba2 = (const float*)d_in[11];
  const float* Wn1 = (const float*)d_in[12];
  const float* bn1 = (const float*)d_in[13];
  const float* Wn2 = (const float*)d_in[14];
  const float* bn2 = (const float*)d_in[15];
  float* out = (float*)d_out;
  float* out_ef = out + (size_t)NN * 64;

  char* ws = (char*)d_ws;
  u16* pk = (u16*)ws;                            // 90112 u16 = 180224 B

  // layout: pk | cnt | part | cursor | bsum | bbase | tup(16B) | agg
  const size_t CNT_OFF  = 180224;                // 200000 B
  const size_t PART_OFF = 380224;                // 200000 B
  const size_t CUR_OFF  = 580224;                // 200000 B
  const size_t BSUM_OFF = 780224;                // 784 B
  const size_t BBAS_OFF = 781008;                // 784 B (+pad to 16B align)
  const size_t TUP_OFF  = 781808;                // NE*16 = 12,800,000 B
  const size_t AGG_OFF  = 13581808;              // NN*64*4 = 12,800,000 B
  const size_t NEED     = AGG_OFF + (size_t)NN * 64 * 4;   // ~26.4 MB

  pack_kernel<<<352, 256, 0, stream>>>(We1, We2, Wa1, Wa2, Wn1, Wn2, pk);

  if (ws_size >= NEED) {
    int*  cnt    = (int*)(ws + CNT_OFF);
    int*  part   = (int*)(ws + PART_OFF);
    int*  cursor = (int*)(ws + CUR_OFF);
    int*  bsum   = (int*)(ws + BSUM_OFF);
    int*  bbase  = (int*)(ws + BBAS_OFF);
    int4* tup    = (int4*)(ws + TUP_OFF);
    float* agg   = (float*)(ws + AGG_OFF);

    hipMemsetAsync(cnt, 0, (size_t)NN * sizeof(int), stream);
    hipMemsetAsync(agg, 0, (size_t)NN * 64 * sizeof(float), stream);
    count_kernel<<<(NE + 255) / 256, 256, 0, stream>>>(dst, cnt);
    scan1_kernel<<<NB, 256, 0, stream>>>(cnt, part, bsum);
    scan2_kernel<<<1, 256, 0, stream>>>(bsum, bbase);
    scan3_kernel<<<NB, 256, 0, stream>>>(part, bbase, cursor);
    fill_kernel<<<(NE + 255) / 256, 256, 0, stream>>>(src, dst, cursor, tup);
    edge_sorted<<<NE / 64, 256, 0, stream>>>(nf, ef, tup,
        pk, be1, pk + 24576, be2, pk + 32768, ba1, pk + 57344, ba2,
        out_ef, agg);
    node_direct<<<(NN + 63) / 64, 256, 0, stream>>>(nf, agg,
        pk + 65536, bn1, pk + 81920, bn2, out);
  } else {
    float* agg = (float*)(ws + CNT_OFF);         // 12.8 MB
    hipMemsetAsync(agg, 0, (size_t)NN * 64 * sizeof(float), stream);
    edge_atomic<<<NE / 64, 256, 0, stream>>>(nf, ef, src, dst,
        pk, be1, pk + 24576, be2, pk + 32768, ba1, pk + 57344, ba2,
        out_ef, agg);
    node_direct<<<(NN + 63) / 64, 256, 0, stream>>>(nf, agg,
        pk + 65536, bn1, pk + 81920, bn2, out);
  }
}

// Round 10
// 770.407 us; speedup vs baseline: 1.0532x; 1.0532x over previous
//
#include <hip/hip_runtime.h>

#define NN 50000
#define NE 800000

typedef float f32x4 __attribute__((ext_vector_type(4)));
typedef short s16x8 __attribute__((ext_vector_type(8)));
typedef unsigned short u16;

__device__ __forceinline__ u16 f2bf(float f) {
  union { float f; unsigned u; } v; v.f = f;
  unsigned r = v.u + 0x7FFFu + ((v.u >> 16) & 1u);
  return (u16)(r >> 16);
}

__device__ __forceinline__ void st_bf4(u16* p, f32x4 v) {
  ushort4 pv;
  pv.x = f2bf(v.x); pv.y = f2bf(v.y); pv.z = f2bf(v.z); pv.w = f2bf(v.w);
  *(ushort4*)p = pv;
}

// pack W[K x N] fp32 -> bf16, fragment-major for 16x16x32 MFMA B-operand
__device__ __forceinline__ void pack_one(const float* __restrict__ W, int N,
                                         u16* __restrict__ out, int t) {
  int j = t & 7, lane = (t >> 3) & 63, f = t >> 9;
  int NT = N >> 4;
  int nt = f % NT, ks = f / NT;
  int row = ks * 32 + ((lane >> 4) << 3) + j;
  int col = nt * 16 + (lane & 15);
  out[t] = f2bf(W[row * N + col]);
}

__global__ void pack_kernel(const float* __restrict__ We1, const float* __restrict__ We2,
                            const float* __restrict__ Wa1, const float* __restrict__ Wa2,
                            const float* __restrict__ Wn1, const float* __restrict__ Wn2,
                            u16* __restrict__ out) {
  int t = blockIdx.x * 256 + threadIdx.x;
  if (t < 24576)      pack_one(We1, 128, out,          t);
  else if (t < 32768) pack_one(We2, 64,  out + 24576,  t - 24576);
  else if (t < 57344) pack_one(Wa1, 128, out + 32768,  t - 32768);
  else if (t < 65536) pack_one(Wa2, 64,  out + 57344,  t - 57344);
  else if (t < 81920) pack_one(Wn1, 128, out + 65536,  t - 65536);
  else if (t < 90112) pack_one(Wn2, 64,  out + 81920,  t - 81920);
}

// ---- shared MLP cores ----
// NOTE: xe and hs may ALIAS (wave-private buffer). Safety: xe is fully
// consumed into the a1 register fragments before the first hs write; a1 is
// reused from registers thereafter. Same-wave DS ops execute in order, and
// __syncthreads() separates every cross-phase RAW/WAR pair.

__device__ __forceinline__ void edge_mlps(
    u16* xe /*stride 200*/, u16* hs /*stride 136*/, int lane,
    const u16* __restrict__ W1e, const float* __restrict__ b1e, const u16* __restrict__ W2e,
    const u16* __restrict__ W1a, const float* __restrict__ b1a, const u16* __restrict__ W2a,
    f32x4 eo[4], f32x4 go[4]) {
  const int m = lane & 15, q = lane >> 4;
  s16x8 a1[6];
  #pragma unroll
  for (int k = 0; k < 6; ++k)
    a1[k] = *(const s16x8*)(xe + m * 200 + k * 32 + q * 8);

  // e-MLP layer 1: [16x192] @ [192x128]
  f32x4 acc[8];
  #pragma unroll
  for (int i = 0; i < 8; ++i) { acc[i][0] = 0.f; acc[i][1] = 0.f; acc[i][2] = 0.f; acc[i][3] = 0.f; }
  #pragma unroll
  for (int nt = 0; nt < 8; ++nt)
    #pragma unroll
    for (int k = 0; k < 6; ++k) {
      s16x8 b = *(const s16x8*)(W1e + ((size_t)(k * 8 + nt) * 64 + lane) * 8);
      acc[nt] = __builtin_amdgcn_mfma_f32_16x16x32_bf16(a1[k], b, acc[nt], 0, 0, 0);
    }
  #pragma unroll
  for (int nt = 0; nt < 8; ++nt) {
    float bv = b1e[nt * 16 + m];
    #pragma unroll
    for (int r = 0; r < 4; ++r) {
      float h = acc[nt][r] + bv;
      h = h > 0.f ? h : 0.f;
      hs[(q * 4 + r) * 136 + nt * 16 + m] = f2bf(h);
    }
  }
  __syncthreads();

  // e-MLP layer 2: [16x128] @ [128x64]
  s16x8 a2[4];
  #pragma unroll
  for (int k = 0; k < 4; ++k)
    a2[k] = *(const s16x8*)(hs + m * 136 + k * 32 + q * 8);
  #pragma unroll
  for (int i = 0; i < 4; ++i) { eo[i][0] = 0.f; eo[i][1] = 0.f; eo[i][2] = 0.f; eo[i][3] = 0.f; }
  #pragma unroll
  for (int nt = 0; nt < 4; ++nt)
    #pragma unroll
    for (int k = 0; k < 4; ++k) {
      s16x8 b = *(const s16x8*)(W2e + ((size_t)(k * 4 + nt) * 64 + lane) * 8);
      eo[nt] = __builtin_amdgcn_mfma_f32_16x16x32_bf16(a2[k], b, eo[nt], 0, 0, 0);
    }

  // gate-MLP layer 1 (reuses a1 registers)
  f32x4 accg[8];
  #pragma unroll
  for (int i = 0; i < 8; ++i) { accg[i][0] = 0.f; accg[i][1] = 0.f; accg[i][2] = 0.f; accg[i][3] = 0.f; }
  #pragma unroll
  for (int nt = 0; nt < 8; ++nt)
    #pragma unroll
    for (int k = 0; k < 6; ++k) {
      s16x8 b = *(const s16x8*)(W1a + ((size_t)(k * 8 + nt) * 64 + lane) * 8);
      accg[nt] = __builtin_amdgcn_mfma_f32_16x16x32_bf16(a1[k], b, accg[nt], 0, 0, 0);
    }
  __syncthreads();   // a2 reads done before hs overwrite
  #pragma unroll
  for (int nt = 0; nt < 8; ++nt) {
    float bv = b1a[nt * 16 + m];
    #pragma unroll
    for (int r = 0; r < 4; ++r) {
      float h = accg[nt][r] + bv;
      h = h > 0.f ? h : 0.f;
      hs[(q * 4 + r) * 136 + nt * 16 + m] = f2bf(h);
    }
  }
  __syncthreads();

  // gate-MLP layer 2
  s16x8 a2g[4];
  #pragma unroll
  for (int k = 0; k < 4; ++k)
    a2g[k] = *(const s16x8*)(hs + m * 136 + k * 32 + q * 8);
  #pragma unroll
  for (int i = 0; i < 4; ++i) { go[i][0] = 0.f; go[i][1] = 0.f; go[i][2] = 0.f; go[i][3] = 0.f; }
  #pragma unroll
  for (int nt = 0; nt < 4; ++nt)
    #pragma unroll
    for (int k = 0; k < 4; ++k) {
      s16x8 b = *(const s16x8*)(W2a + ((size_t)(k * 4 + nt) * 64 + lane) * 8);
      go[nt] = __builtin_amdgcn_mfma_f32_16x16x32_bf16(a2g[k], b, go[nt], 0, 0, 0);
    }
}

__device__ __forceinline__ void node_mlp(
    u16* xn /*stride 136*/, u16* hn /*stride 136, may alias xn*/, int lane,
    const u16* __restrict__ W1n, const float* __restrict__ b1n, const u16* __restrict__ W2n,
    f32x4 o[4]) {
  const int m = lane & 15, q = lane >> 4;
  s16x8 a1[4];
  #pragma unroll
  for (int k = 0; k < 4; ++k)
    a1[k] = *(const s16x8*)(xn + m * 136 + k * 32 + q * 8);
  f32x4 acc[8];
  #pragma unroll
  for (int i = 0; i < 8; ++i) { acc[i][0] = 0.f; acc[i][1] = 0.f; acc[i][2] = 0.f; acc[i][3] = 0.f; }
  #pragma unroll
  for (int nt = 0; nt < 8; ++nt)
    #pragma unroll
    for (int k = 0; k < 4; ++k) {
      s16x8 b = *(const s16x8*)(W1n + ((size_t)(k * 8 + nt) * 64 + lane) * 8);
      acc[nt] = __builtin_amdgcn_mfma_f32_16x16x32_bf16(a1[k], b, acc[nt], 0, 0, 0);
    }
  #pragma unroll
  for (int nt = 0; nt < 8; ++nt) {
    float bv = b1n[nt * 16 + m];
    #pragma unroll
    for (int r = 0; r < 4; ++r) {
      float h = acc[nt][r] + bv;
      h = h > 0.f ? h : 0.f;
      hn[(q * 4 + r) * 136 + nt * 16 + m] = f2bf(h);
    }
  }
  __syncthreads();
  s16x8 a2[4];
  #pragma unroll
  for (int k = 0; k < 4; ++k)
    a2[k] = *(const s16x8*)(hn + m * 136 + k * 32 + q * 8);
  #pragma unroll
  for (int i = 0; i < 4; ++i) { o[i][0] = 0.f; o[i][1] = 0.f; o[i][2] = 0.f; o[i][3] = 0.f; }
  #pragma unroll
  for (int nt = 0; nt < 4; ++nt)
    #pragma unroll
    for (int k = 0; k < 4; ++k) {
      s16x8 b = *(const s16x8*)(W2n + ((size_t)(k * 4 + nt) * 64 + lane) * 8);
      o[nt] = __builtin_amdgcn_mfma_f32_16x16x32_bf16(a2[k], b, o[nt], 0, 0, 0);
    }
}

// ---- edge kernel: original order, atomics into agg, aliased LDS ----
// LDS/block: 4*3200*2 (aliased xe/hs) + 256 (sdst) = 25856 B -> 6 blocks/CU
// by LDS; VGPR ~80 -> 512/80 = 6 blocks/CU.  launch_bounds kept at (256,3)
// so the register allocator is NOT capped (R3's spill trap); the higher
// occupancy comes from the resource limits at runtime.

__global__ __launch_bounds__(256, 3)
void edge_kernel(const float* __restrict__ nf, const float* __restrict__ ef,
                 const int* __restrict__ src, const int* __restrict__ dst,
                 const u16* __restrict__ W1e, const float* __restrict__ b1e,
                 const u16* __restrict__ W2e, const float* __restrict__ b2e,
                 const u16* __restrict__ W1a, const float* __restrict__ b1a,
                 const u16* __restrict__ W2a, const float* __restrict__ b2a,
                 float* __restrict__ out_ef, float* __restrict__ agg) {
  __shared__ u16 buf[4][16 * 200];
  __shared__ int sdst[4][16];
  const int w = threadIdx.x >> 6, lane = threadIdx.x & 63;
  const int e0 = blockIdx.x * 64 + w * 16;
  const int er = lane >> 4, c4 = (lane & 15) * 4;
  u16* const xe = buf[w];   // stride 200
  u16* const hs = buf[w];   // stride 136 (aliases xe)

  #pragma unroll
  for (int g = 0; g < 4; ++g) {
    int el = g * 4 + er;
    int e = e0 + el;
    int s = src[e], d = dst[e];
    if (c4 == 0) sdst[w][el] = d;
    f32x4 fs = *(const f32x4*)(nf + (size_t)s * 64 + c4);
    f32x4 fd = *(const f32x4*)(nf + (size_t)d * 64 + c4);
    f32x4 fe = *(const f32x4*)(ef + (size_t)e * 64 + c4);
    u16* row = xe + el * 200;
    st_bf4(row + c4, fs);
    st_bf4(row + 64 + c4, fd);
    st_bf4(row + 128 + c4, fe);
  }
  __syncthreads();

  f32x4 eo[4], go[4];
  edge_mlps(xe, hs, lane, W1e, b1e, W2e, W1a, b1a, W2a, eo, go);

  const int m = lane & 15, q = lane >> 4;
  #pragma unroll
  for (int nt = 0; nt < 4; ++nt) {
    int col = nt * 16 + m;
    float be2v = b2e[col], ba2v = b2a[col];
    #pragma unroll
    for (int r = 0; r < 4; ++r) {
      int rowi = q * 4 + r;
      int e = e0 + rowi;
      float ev = eo[nt][r] + be2v;
      float gv = go[nt][r] + ba2v;
      float gs = 1.f / (1.f + __expf(-gv));
      float val = gs * ev;
      out_ef[(size_t)e * 64 + col] = val;
      atomicAdd(agg + (size_t)sdst[w][rowi] * 64 + col, val);
    }
  }
}

// ---- node kernel: reads dense pre-aggregated agg, aliased LDS (8960 B) ----

__global__ __launch_bounds__(256, 4)
void node_kernel(const float* __restrict__ nf, const float* __restrict__ agg,
                 const u16* __restrict__ W1n, const float* __restrict__ b1n,
                 const u16* __restrict__ W2n, const float* __restrict__ b2n,
                 float* __restrict__ out_nf) {
  __shared__ u16 buf[4][16 * 136];
  const int w = threadIdx.x >> 6, lane = threadIdx.x & 63;
  const int n0 = blockIdx.x * 64 + w * 16;
  const int er = lane >> 4, c4 = (lane & 15) * 4;
  u16* const xn = buf[w];
  u16* const hn = buf[w];   // aliases xn (xn consumed into a1 before hn write)

  #pragma unroll
  for (int g = 0; g < 4; ++g) {
    int nl = g * 4 + er;
    int n = n0 + nl; if (n >= NN) n = NN - 1;
    f32x4 fa = *(const f32x4*)(agg + (size_t)n * 64 + c4);
    f32x4 fn4 = *(const f32x4*)(nf + (size_t)n * 64 + c4);
    u16* row = xn + nl * 136;
    st_bf4(row + c4, fa);
    st_bf4(row + 64 + c4, fn4);
  }
  __syncthreads();

  f32x4 o[4];
  node_mlp(xn, hn, lane, W1n, b1n, W2n, o);

  const int m = lane & 15, q = lane >> 4;
  #pragma unroll
  for (int nt = 0; nt < 4; ++nt) {
    int col = nt * 16 + m;
    float bv = b2n[col];
    #pragma unroll
    for (int r = 0; r < 4; ++r) {
      int n = n0 + q * 4 + r;
      if (n < NN) out_nf[(size_t)n * 64 + col] = o[nt][r] + bv;
    }
  }
}

extern "C" void kernel_launch(void* const* d_in, const int* in_sizes, int n_in,
                              void* d_out, int out_size, void* d_ws, size_t ws_size,
                              hipStream_t stream) {
  const float* nf  = (const float*)d_in[0];
  const float* ef  = (const float*)d_in[1];
  const int*   src = (const int*)d_in[2];
  const int*   dst = (const int*)d_in[3];
  const float* We1 = (const float*)d_in[4];
  const float* be1 = (const float*)d_in[5];
  const float* We2 = (const float*)d_in[6];
  const float* be2 = (const float*)d_in[7];
  const float* Wa1 = (const float*)d_in[8];
  const float* ba1 = (const float*)d_in[9];
  const float* Wa2 = (const float*)d_in[10];
  const float* ba2 = (const float*)d_in[11];
  const float* Wn1 = (const float*)d_in[12];
  const float* bn1 = (const float*)d_in[13];
  const float* Wn2 = (const float*)d_in[14];
  const float* bn2 = (const float*)d_in[15];
  float* out = (float*)d_out;
  float* out_ef = out + (size_t)NN * 64;

  char* ws = (char*)d_ws;
  u16* pk    = (u16*)ws;                           // 90112 u16 = 180224 B
  float* agg = (float*)(ws + 180224);              // NN*64*4 = 12.8 MB

  hipMemsetAsync(agg, 0, (size_t)NN * 64 * sizeof(float), stream);
  pack_kernel<<<352, 256, 0, stream>>>(We1, We2, Wa1, Wa2, Wn1, Wn2, pk);
  edge_kernel<<<NE / 64, 256, 0, stream>>>(nf, ef, src, dst,
      pk, be1, pk + 24576, be2, pk + 32768, ba1, pk + 57344, ba2,
      out_ef, agg);
  node_kernel<<<(NN + 63) / 64, 256, 0, stream>>>(nf, agg,
      pk + 65536, bn1, pk + 81920, bn2, out);
}